// Round 1
// baseline (309.773 us; speedup 1.0000x reference)
//
#include <hip/hip_runtime.h>

// HAttention1D: b=4,h=8,n=8192,d=64,bsz=16, levels 0..8.
// out[i] = sum_l y_l[i>>l] / (sum_l a_l[i>>l] + 1e-8); level 0: block-diagonal
// 16x16 attention; level l>=1: query block attends sibling block (B>>l)^1 on
// mean-pooled q,k (q pre-scaled d^-0.5) / sum-pooled v.
//
// R5: (a) pool split per-tensor via gridDim.z=3 (was 4 blocks/CU = 50% occ cap);
// (b) V pyramid stored column-major per 16-row block -> pool v-stores vectorize
// (uint4) and attend's PV fragment read becomes one ds_read_b64 (was 16 scalar
// u16 reads/level); (c) q/k MFMA fragments loaded directly global->VGPR (the LDS
// staging was pure lane redistribution); (d) attend packs 4 independent waves
// per 256-thread WG (single-wave WGs capped resident waves/CU).
// Values & op order identical to R4 -> absmax unchanged.

#define NBH 32
#define SEQN 8192
#define DIM 64
#define ROWS_F16 16352   // 8192+4096+...+32 (levels 0..8)
#define VSTR 20          // LDS column stride (halves): 8B-aligned, conflict-free b64 reads

typedef _Float16 v2h __attribute__((ext_vector_type(2)));
typedef _Float16 v4h __attribute__((ext_vector_type(4)));
typedef _Float16 v8h __attribute__((ext_vector_type(8)));
typedef float v4f __attribute__((ext_vector_type(4)));
typedef uint4 uint4a __attribute__((may_alias));
typedef uint2 uint2a __attribute__((may_alias));
typedef unsigned int uinta __attribute__((may_alias));

__constant__ int OFF16[9] = {0, 8192, 12288, 14336, 15360, 15872, 16128, 16256, 16320};

// ---------------- pool ----------------
// mode (blockIdx.z): 0=q (mean, *0.125), 1=k (mean), 2=v (sum, col-major blocks).
// q,k row-major fp16. v: per 16-row block, [64 cols][16 rows] (col-major) so each
// pool thread (owning one column) writes 16 contiguous halves per block.
__global__ __launch_bounds__(256) void pool_kernel(
    const float* __restrict__ q, const float* __restrict__ k, const float* __restrict__ v,
    _Float16* __restrict__ qp, _Float16* __restrict__ kp, _Float16* __restrict__ vp) {
    const int chunk = blockIdx.x, z = blockIdx.y, mode = blockIdx.z;
    const int t = threadIdx.x, d = t & 63, g = t >> 6;
    const float* __restrict__ in = (mode == 0) ? q : (mode == 1) ? k : v;
    _Float16* __restrict__ pyr = (mode == 0) ? qp : (mode == 1) ? kp : vp;
    const float fs = (mode == 0) ? 0.125f : 1.0f;   // fine-level scale
    const float sc = (mode == 2) ? 1.0f : 0.5f;     // pool scale (sum vs mean)
    const bool vlay = (mode == 2);
    __shared__ float lds[4][64];
    const int rowbase = chunk * 256 + g * 64;
    const size_t zb = (size_t)z * ROWS_F16;

    float val[64];
    const float* src = in + ((size_t)z * SEQN + rowbase) * DIM + d;
#pragma unroll
    for (int r = 0; r < 64; ++r) val[r] = src[(size_t)r * DIM] * fs;

    // ---- fine level ----
    if (!vlay) {
        const size_t b0 = (zb + rowbase) * DIM + d;
#pragma unroll
        for (int r = 0; r < 64; ++r) pyr[b0 + (size_t)r * DIM] = (_Float16)val[r];
    } else {
#pragma unroll
        for (int b = 0; b < 4; ++b) {
            v8h h0, h1;
#pragma unroll
            for (int i = 0; i < 8; ++i) {
                h0[i] = (_Float16)val[b * 16 + i];
                h1[i] = (_Float16)val[b * 16 + 8 + i];
            }
            _Float16* dst = pyr + (zb + rowbase + b * 16) * DIM + d * 16;
            ((uint4a*)dst)[0] = __builtin_bit_cast(uint4, h0);
            ((uint4a*)dst)[1] = __builtin_bit_cast(uint4, h1);
        }
    }

    // ---- levels 1..6 (local to this 64-row thread-group) ----
#pragma unroll
    for (int l = 1; l <= 6; ++l) {
        const int nr = 64 >> l;
#pragma unroll
        for (int r = 0; r < nr; ++r) val[r] = (val[2 * r] + val[2 * r + 1]) * sc;
        const int row0 = rowbase >> l;
        if (!vlay) {
            const size_t base = (zb + OFF16[l] + row0) * DIM + d;
#pragma unroll
            for (int r = 0; r < nr; ++r) pyr[base + (size_t)r * DIM] = (_Float16)val[r];
        } else {
            if (nr >= 16) {
#pragma unroll
                for (int b = 0; b < nr / 16; ++b) {
                    v8h h0, h1;
#pragma unroll
                    for (int i = 0; i < 8; ++i) {
                        h0[i] = (_Float16)val[b * 16 + i];
                        h1[i] = (_Float16)val[b * 16 + 8 + i];
                    }
                    _Float16* dst = pyr + (zb + OFF16[l] + row0 + b * 16) * DIM + d * 16;
                    ((uint4a*)dst)[0] = __builtin_bit_cast(uint4, h0);
                    ((uint4a*)dst)[1] = __builtin_bit_cast(uint4, h1);
                }
            } else {
                const int r4 = row0 & 15;
                _Float16* dst = pyr + (zb + OFF16[l] + (row0 & ~15)) * DIM + d * 16 + r4;
                if (nr == 8) {
                    v8h h0;
#pragma unroll
                    for (int i = 0; i < 8; ++i) h0[i] = (_Float16)val[i];
                    *(uint4a*)dst = __builtin_bit_cast(uint4, h0);  // r4 in {0,8}: 16B-aligned
                } else if (nr == 4) {
                    v4h h;
#pragma unroll
                    for (int i = 0; i < 4; ++i) h[i] = (_Float16)val[i];
                    *(uint2a*)dst = __builtin_bit_cast(uint2, h);   // r4 = g*4: 8B-aligned
                } else if (nr == 2) {
                    v2h h;
                    h[0] = (_Float16)val[0];
                    h[1] = (_Float16)val[1];
                    *(uinta*)dst = __builtin_bit_cast(unsigned int, h);  // r4 even: 4B-aligned
                } else {
                    dst[0] = (_Float16)val[0];
                }
            }
        }
    }

    // ---- levels 7,8 (cross-group via LDS) ----
    lds[g][d] = val[0];
    __syncthreads();
    if (g == 0) {
        const float l7a = (lds[0][d] + lds[1][d]) * sc;
        const float l7b = (lds[2][d] + lds[3][d]) * sc;
        const float l8v = (l7a + l7b) * sc;
        if (!vlay) {
            const size_t b7 = (zb + OFF16[7] + chunk * 2) * DIM + d;
            pyr[b7] = (_Float16)l7a;
            pyr[b7 + DIM] = (_Float16)l7b;
            pyr[(zb + OFF16[8] + chunk) * DIM + d] = (_Float16)l8v;
        } else {
            const int a7 = chunk * 2;
            _Float16* d7 = pyr + (zb + OFF16[7] + (a7 & ~15)) * DIM + d * 16 + (a7 & 15);
            v2h h7;
            h7[0] = (_Float16)l7a;
            h7[1] = (_Float16)l7b;
            *(uinta*)d7 = __builtin_bit_cast(unsigned int, h7);
            _Float16* d8 = pyr + (zb + OFF16[8] + (chunk & ~15)) * DIM + d * 16 + (chunk & 15);
            *d8 = (_Float16)l8v;
        }
    }
}

// ---------------- attend ----------------
__device__ __forceinline__ float bperm(int lane, float x) {
    return __int_as_float(__builtin_amdgcn_ds_bpermute(lane << 2, __float_as_int(x)));
}

// 256 threads = 4 independent waves; wave w handles output block B = bx*4+w.
// q/k fragments: direct global->VGPR (row m, 16B at col quad*8 / 32+quad*8).
// v: col-major 16-row blocks staged to LDS (stride VSTR=20 halves); PV fragment
// (rows quad*4..+3, col nt*16+m) = one aligned 8B LDS read.
__global__ __launch_bounds__(256) void attend_kernel(
    const _Float16* __restrict__ qp, const _Float16* __restrict__ kp,
    const _Float16* __restrict__ vp, float* __restrict__ out) {
    __shared__ _Float16 vsh[4][2][64 * VSTR];
    const int tid = threadIdx.x;
    const int t = tid & 63, w = tid >> 6;
    const int m = t & 15, quad = t >> 4;
    const int B = blockIdx.x * 4 + w;
    const int z = blockIdx.y;
    const size_t zp = (size_t)z * ROWS_F16 * DIM;

    v4f Y[4];
    float A[4];
#pragma unroll
    for (int nt = 0; nt < 4; ++nt) Y[nt] = (v4f){0.f, 0.f, 0.f, 0.f};
#pragma unroll
    for (int r = 0; r < 4; ++r) A[r] = 0.f;

    auto issue = [&](int l, v8h& qf0, v8h& qf1, v8h& kf0, v8h& kf1, uint4& v0, uint4& v1) {
        const int c = (l == 0) ? 16 : ((l <= 4) ? (16 >> l) : 1);
        const int qrow0 = (B * 16) >> l;
        const int kb = (l == 0) ? B : ((B >> l) ^ 1);
        const int qm = (m < c) ? m : (c - 1);  // clamp: duplicate valid rows, cols >=c unused
        const uint4a* qr = (const uint4a*)(qp + zp + (size_t)(OFF16[l] + qrow0 + qm) * DIM);
        qf0 = __builtin_bit_cast(v8h, qr[quad]);
        qf1 = __builtin_bit_cast(v8h, qr[4 + quad]);
        const uint4a* kr = (const uint4a*)(kp + zp + (size_t)(OFF16[l] + kb * 16 + m) * DIM);
        kf0 = __builtin_bit_cast(v8h, kr[quad]);
        kf1 = __builtin_bit_cast(v8h, kr[4 + quad]);
        const uint4a* vsrc = (const uint4a*)(vp + zp + (size_t)(OFF16[l] + kb * 16) * DIM);
        v0 = vsrc[t];
        v1 = vsrc[t + 64];
    };

    auto stagev = [&](_Float16* vs, uint4 v0, uint4 v1) {
        // global col-major block: uint4 u -> col=u>>1, rows (u&1)*8..+7 of that col
        const int col = t >> 1, h = (t & 1) * 8;
        uint2a* p0 = (uint2a*)(vs + col * VSTR + h);
        p0[0] = make_uint2(v0.x, v0.y);
        p0[1] = make_uint2(v0.z, v0.w);
        uint2a* p1 = (uint2a*)(vs + (32 + col) * VSTR + h);
        p1[0] = make_uint2(v1.x, v1.y);
        p1[1] = make_uint2(v1.z, v1.w);
    };

    auto do_level = [&](int l, v8h qf0, v8h qf1, v8h kf0, v8h kf1, const _Float16* vs) {
        // S^T[j][m] = sum_d K[j][d]*Qs[m][d]; A-frag rows = K, B-frag rows = Q.
        v4f s4 = (v4f){0.f, 0.f, 0.f, 0.f};
        s4 = __builtin_amdgcn_mfma_f32_16x16x32_f16(kf0, qf0, s4, 0, 0, 0);
        s4 = __builtin_amdgcn_mfma_f32_16x16x32_f16(kf1, qf1, s4, 0, 0, 0);
        float mx = fmaxf(fmaxf(s4[0], s4[1]), fmaxf(s4[2], s4[3]));
        mx = fmaxf(mx, __shfl_xor(mx, 16, 64));
        mx = fmaxf(mx, __shfl_xor(mx, 32, 64));
        float e0 = __expf(s4[0] - mx), e1 = __expf(s4[1] - mx);
        float e2 = __expf(s4[2] - mx), e3 = __expf(s4[3] - mx);
        float sm = e0 + e1 + e2 + e3;
        sm += __shfl_xor(sm, 16, 64);
        sm += __shfl_xor(sm, 32, 64);
        const int sl = (m >> l) + (quad << 4);
        v4h pf;
        pf[0] = (_Float16)bperm(sl, e0);
        pf[1] = (_Float16)bperm(sl, e1);
        pf[2] = (_Float16)bperm(sl, e2);
        pf[3] = (_Float16)bperm(sl, e3);
#pragma unroll
        for (int nt = 0; nt < 4; ++nt) {
            v4h vf = __builtin_bit_cast(v4h, *(const uint2a*)(vs + (nt * 16 + m) * VSTR + quad * 4));
            Y[nt] = __builtin_amdgcn_mfma_f32_16x16x16f16(pf, vf, Y[nt], 0, 0, 0);
        }
#pragma unroll
        for (int r = 0; r < 4; ++r) A[r] += bperm((quad * 4 + r) >> l, sm);
    };

    v8h q0{}, q1{}, k0{}, k1{};
    uint4 v0{}, v1{};
    issue(0, q0, q1, k0, k1, v0, v1);
#pragma unroll
    for (int l = 0; l <= 8; ++l) {
        _Float16* vs = &vsh[w][l & 1][0];
        stagev(vs, v0, v1);
        v8h nq0{}, nq1{}, nk0{}, nk1{};
        uint4 nv0{}, nv1{};
        if (l < 8) issue(l + 1, nq0, nq1, nk0, nk1, nv0, nv1);
        do_level(l, q0, q1, k0, k1, vs);
        q0 = nq0; q1 = nq1; k0 = nk0; k1 = nk1; v0 = nv0; v1 = nv1;
    }

    // ---- epilogue ----
    float* ob = out + (size_t)z * SEQN * DIM + (size_t)B * 16 * DIM;
#pragma unroll
    for (int r = 0; r < 4; ++r) {
        const float inv = 1.0f / (A[r] + 1e-8f);
#pragma unroll
        for (int nt = 0; nt < 4; ++nt)
            ob[(quad * 4 + r) * 64 + nt * 16 + m] = Y[nt][r] * inv;
    }
}

extern "C" void kernel_launch(void* const* d_in, const int* in_sizes, int n_in,
                              void* d_out, int out_size, void* d_ws, size_t ws_size,
                              hipStream_t stream) {
    const float* q = (const float*)d_in[0];
    const float* k = (const float*)d_in[1];
    const float* v = (const float*)d_in[2];
    float* out = (float*)d_out;

    // ws: 3 fp16 pyramids (fine+levels 1..8) = 3 * 66,977,792 B; prior rounds
    // confirmed ws_size >= this (FINE16 branch ran).
    const size_t T16 = (size_t)NBH * ROWS_F16 * DIM * sizeof(_Float16);
    char* w = (char*)d_ws;
    _Float16* qp = (_Float16*)w;
    _Float16* kp = (_Float16*)(w + T16);
    _Float16* vp = (_Float16*)(w + 2 * T16);

    pool_kernel<<<dim3(SEQN / 256, NBH, 3), 256, 0, stream>>>(q, k, v, qp, kp, vp);
    attend_kernel<<<dim3(SEQN / 16 / 4, NBH), 256, 0, stream>>>(qp, kp, vp, out);
}